// Round 3
// baseline (418.329 us; speedup 1.0000x reference)
//
#include <hip/hip_runtime.h>

#define NU 4096
#define NI 8192
#define ND 64
#define NTOT 12288
#define CT 8           // top split-K chunks  (K=NU,  ck=512)
#define CB 16          // bottom split-K chunks (K=NI, ck=512)
#define CK 512

typedef unsigned short u16;
typedef unsigned long long u64;

__device__ __forceinline__ u16 f2bf(float f) {
    union { float f; unsigned int u; } v; v.f = f;
    unsigned int u = v.u;
    u += 0x7FFFu + ((u >> 16) & 1u);   // round-to-nearest-even
    return (u16)(u >> 16);
}

typedef short frag8 __attribute__((ext_vector_type(8)));
typedef float f32x4 __attribute__((ext_vector_type(4)));

// ---------------------------------------------------------------------------
// K0: read int32 adjacency once; emit BIT-PACKED A (NU x NI/64 u64) and
// AT (NI x NU/64 u64) via __ballot, plus degree sums. Edge-read bound.
// ---------------------------------------------------------------------------
__global__ __launch_bounds__(256) void k_prep_pack(const int* __restrict__ edge,
        u64* __restrict__ Apk, u64* __restrict__ ATpk,
        int* __restrict__ deg_u, int* __restrict__ deg_i) {
    __shared__ u16 cbl[64][4];
    const int t = threadIdx.x, lane = t & 63, w = t >> 6;
    const int u0 = blockIdx.y * 64, i0 = blockIdx.x * 64;
    int v[16];
    #pragma unroll
    for (int j = 0; j < 16; j++)
        v[j] = edge[(size_t)(u0 + w * 16 + j) * NI + i0 + lane];
    unsigned int cb = 0;
    #pragma unroll
    for (int j = 0; j < 16; j++) {
        u64 bal = __ballot(v[j] != 0);
        cb |= (v[j] != 0 ? 1u : 0u) << j;
        if (lane == 0) {
            Apk[(size_t)(u0 + w * 16 + j) * (NI / 64) + (i0 >> 6)] = bal;
            atomicAdd(&deg_u[u0 + w * 16 + j], (int)__popcll(bal));
        }
    }
    cbl[lane][w] = (u16)cb;
    __syncthreads();
    if (t < 64) {
        u64 cw = (u64)cbl[t][0] | ((u64)cbl[t][1] << 16) |
                 ((u64)cbl[t][2] << 32) | ((u64)cbl[t][3] << 48);
        ATpk[(size_t)(i0 + t) * (NU / 64) + (u0 >> 6)] = cw;
        atomicAdd(&deg_i[i0 + t], (int)__popcll(cw));
    }
}

// ---------------------------------------------------------------------------
// K1: degree->scale arrays + layer-0 B operands, embedding-major (64 x K).
// ---------------------------------------------------------------------------
__global__ __launch_bounds__(256) void k_scale0(const float* __restrict__ x,
        const int* __restrict__ deg_u, const int* __restrict__ deg_i,
        float* __restrict__ dsu, float* __restrict__ dsi,
        u16* __restrict__ BuT, u16* __restrict__ BiT) {
    const int t = threadIdx.x;
    const int r0 = blockIdx.x * 64;
    const int r4 = t >> 4, c4 = t & 15;
    if (t < 64) {
        int gr = r0 + t;
        int d = (gr < NU) ? deg_u[gr] : deg_i[gr - NU];
        float sc = d > 0 ? rsqrtf((float)d) : 0.f;
        if (gr < NU) dsu[gr] = sc; else dsi[gr - NU] = sc;
    }
    float y[4][4];
    #pragma unroll
    for (int j = 0; j < 4; j++) {
        int gr = r0 + r4 * 4 + j;
        int d = (gr < NU) ? deg_u[gr] : deg_i[gr - NU];
        float sc = d > 0 ? rsqrtf((float)d) : 0.f;
        float4 xv = *(const float4*)(x + (size_t)gr * ND + c4 * 4);
        y[j][0] = xv.x * sc; y[j][1] = xv.y * sc;
        y[j][2] = xv.z * sc; y[j][3] = xv.w * sc;
    }
    u16* dst; size_t stride; int col0;
    if (r0 < NU) { dst = BuT; stride = NU; col0 = r0; }
    else         { dst = BiT; stride = NI; col0 = r0 - NU; }
    #pragma unroll
    for (int k = 0; k < 4; k++) {
        ushort4 w;
        w.x = f2bf(y[0][k]); w.y = f2bf(y[1][k]);
        w.z = f2bf(y[2][k]); w.w = f2bf(y[3][k]);
        *(ushort4*)(dst + (size_t)(c4 * 4 + k) * stride + col0 + r4 * 4) = w;
    }
}

// ---------------------------------------------------------------------------
// K2: split-K partial GEMM from BIT-PACKED A. No LDS, no barriers.
// 2048 blocks: bx<1024 top (AT@Bu, 128 tiles x 8 chunks), else bottom
// (A@Bi, 64 tiles x 16 chunks). Wave = 32x32 sub-tile (2 row x 2 col
// 16x16 MFMA tiles). A expanded bit->bf16 in registers; B loaded dwordx4.
// ---------------------------------------------------------------------------
__global__ __launch_bounds__(256, 4) void k_gemm_bit(
        const u64* __restrict__ Apk, const u64* __restrict__ ATpk,
        const u16* __restrict__ BuT, const u16* __restrict__ BiT,
        float* __restrict__ Ptop, float* __restrict__ Pbot) {
    const int t = threadIdx.x, bx = blockIdx.x;
    const int lane = t & 63, lr = lane & 15, lg = lane >> 4;
    const int w = t >> 6, wr = (w >> 1) * 32, wc = (w & 1) * 32;
    const u64* Ab; const u16* Bp; int wpr, Kstr, kbase; float* Pout;
    if (bx < 1024) {
        int tile = bx >> 3, chunk = bx & 7;
        Ab = ATpk + (size_t)(tile * 64) * (NU / 64);
        wpr = NU / 64; Bp = BuT; Kstr = NU; kbase = chunk * CK;
        Pout = Ptop + ((size_t)chunk * NI + tile * 64) * ND;
    } else {
        int b2 = bx - 1024;
        int tile = b2 >> 4, chunk = b2 & 15;
        Ab = Apk + (size_t)(tile * 64) * (NI / 64);
        wpr = NI / 64; Bp = BiT; Kstr = NI; kbase = chunk * CK;
        Pout = Pbot + ((size_t)chunk * NU + tile * 64) * ND;
    }
    const u64* pa0 = Ab + (size_t)(wr + lr) * wpr + (kbase >> 6);
    const u64* pa1 = pa0 + (size_t)16 * wpr;
    const u16* pb0 = Bp + (size_t)(wc + lr) * Kstr + kbase + lg * 8;
    const u16* pb1 = pb0 + (size_t)16 * Kstr;

    f32x4 acc[2][2];
    #pragma unroll
    for (int a = 0; a < 2; a++)
        #pragma unroll
        for (int b = 0; b < 2; b++) acc[a][b] = f32x4{0.f, 0.f, 0.f, 0.f};

    #pragma unroll
    for (int kk = 0; kk < CK / 64; kk++) {
        u64 w0 = pa0[kk], w1 = pa1[kk];
        #pragma unroll
        for (int sh = 0; sh < 2; sh++) {
            const int base = sh * 32 + lg * 8;
            unsigned int b0 = (unsigned int)(w0 >> base) & 0xFFu;
            unsigned int b1 = (unsigned int)(w1 >> base) & 0xFFu;
            frag8 a0, a1;
            #pragma unroll
            for (int j = 0; j < 8; j++) {
                a0[j] = (short)(((b0 >> j) & 1u) ? 0x3F80 : 0);
                a1[j] = (short)(((b1 >> j) & 1u) ? 0x3F80 : 0);
            }
            frag8 bf0 = *(const frag8*)(pb0 + kk * 64 + sh * 32);
            frag8 bf1 = *(const frag8*)(pb1 + kk * 64 + sh * 32);
            acc[0][0] = __builtin_amdgcn_mfma_f32_16x16x32_bf16(a0, bf0, acc[0][0], 0, 0, 0);
            acc[1][0] = __builtin_amdgcn_mfma_f32_16x16x32_bf16(a1, bf0, acc[1][0], 0, 0, 0);
            acc[0][1] = __builtin_amdgcn_mfma_f32_16x16x32_bf16(a0, bf1, acc[0][1], 0, 0, 0);
            acc[1][1] = __builtin_amdgcn_mfma_f32_16x16x32_bf16(a1, bf1, acc[1][1], 0, 0, 0);
        }
    }
    #pragma unroll
    for (int rt = 0; rt < 2; rt++)
        #pragma unroll
        for (int ct = 0; ct < 2; ct++)
            #pragma unroll
            for (int jj = 0; jj < 4; jj++)
                Pout[(size_t)(wr + rt * 16 + lg * 4 + jj) * ND + wc + ct * 16 + lr]
                    = acc[rt][ct][jj];
}

// ---------------------------------------------------------------------------
// K3: reduce partials (hardcoded, fully unrolled chunk loops), apply output
// scale, acc/out logic, emit next-layer B operands.
// ---------------------------------------------------------------------------
__global__ __launch_bounds__(256) void k_reduce(
        const float* __restrict__ Ptop, const float* __restrict__ Pbot,
        const float* __restrict__ dsu, const float* __restrict__ dsi,
        float* __restrict__ accbuf, u16* __restrict__ BuTn,
        u16* __restrict__ BiTn, float* __restrict__ out, int layer) {
    const int t = threadIdx.x;
    const int r0 = blockIdx.x * 64;
    const int r4 = t >> 4, c4 = t & 15;
    float y[4][4];
    #pragma unroll
    for (int j = 0; j < 4; j++) {
        const int grow = r0 + r4 * 4 + j;
        float sx = 0.f, sy = 0.f, sz = 0.f, sw = 0.f, so;
        if (r0 < NI) {
            const float* p = Ptop + (size_t)grow * ND + c4 * 4;
            #pragma unroll
            for (int c = 0; c < CT; c++) {
                float4 v = *(const float4*)(p + (size_t)c * NI * ND);
                sx += v.x; sy += v.y; sz += v.z; sw += v.w;
            }
            so = dsi[grow];
        } else {
            const float* p = Pbot + (size_t)(grow - NI) * ND + c4 * 4;
            #pragma unroll
            for (int c = 0; c < CB; c++) {
                float4 v = *(const float4*)(p + (size_t)c * NU * ND);
                sx += v.x; sy += v.y; sz += v.z; sw += v.w;
            }
            so = dsu[grow - NI];
        }
        y[j][0] = sx * so; y[j][1] = sy * so; y[j][2] = sz * so; y[j][3] = sw * so;
    }
    #pragma unroll
    for (int j = 0; j < 4; j++) {
        const int grow = r0 + r4 * 4 + j;
        size_t o = (size_t)grow * ND + c4 * 4;
        float4 w;
        if (layer == 0) {
            w.x = y[j][0]; w.y = y[j][1]; w.z = y[j][2]; w.w = y[j][3];
            *(float4*)(accbuf + o) = w;
        } else if (layer == 1) {
            float4 a = *(const float4*)(accbuf + o);
            w.x = a.x + y[j][0]; w.y = a.y + y[j][1];
            w.z = a.z + y[j][2]; w.w = a.w + y[j][3];
            *(float4*)(accbuf + o) = w;
        } else {
            float4 a = *(const float4*)(accbuf + o);
            w.x = (a.x + y[j][0]) * 0.25f; w.y = (a.y + y[j][1]) * 0.25f;
            w.z = (a.z + y[j][2]) * 0.25f; w.w = (a.w + y[j][3]) * 0.25f;
            *(float4*)(out + o) = w;
        }
    }
    if (layer != 2) {
        float fn[4];
        #pragma unroll
        for (int j = 0; j < 4; j++) {
            int grow = r0 + r4 * 4 + j;
            fn[j] = (grow < NU) ? dsu[grow] : dsi[grow - NU];
        }
        u16* dst; size_t stride; int col0;
        if (r0 < NU) { dst = BuTn; stride = NU; col0 = r0; }
        else         { dst = BiTn; stride = NI; col0 = r0 - NU; }
        #pragma unroll
        for (int k = 0; k < 4; k++) {
            ushort4 w;
            w.x = f2bf(y[0][k] * fn[0]); w.y = f2bf(y[1][k] * fn[1]);
            w.z = f2bf(y[2][k] * fn[2]); w.w = f2bf(y[3][k] * fn[3]);
            *(ushort4*)(dst + (size_t)(c4 * 4 + k) * stride + col0 + r4 * 4) = w;
        }
    }
}

extern "C" void kernel_launch(void* const* d_in, const int* in_sizes, int n_in,
                              void* d_out, int out_size, void* d_ws, size_t ws_size,
                              hipStream_t stream) {
    (void)in_sizes; (void)n_in; (void)out_size; (void)ws_size;
    const float* x    = (const float*)d_in[0];
    const int*   edge = (const int*)d_in[1];
    float* out = (float*)d_out;

    char* ws = (char*)d_ws;
    size_t off = 0;
    u64* Apk  = (u64*)(ws + off); off += (size_t)NU * (NI / 64) * 8;   // 4 MiB
    u64* ATpk = (u64*)(ws + off); off += (size_t)NI * (NU / 64) * 8;   // 4 MiB
    int* deg_u = (int*)(ws + off); off += (size_t)NU * 4;
    int* deg_i = (int*)(ws + off); off += (size_t)NI * 4;
    float* dsu = (float*)(ws + off); off += (size_t)NU * 4;
    float* dsi = (float*)(ws + off); off += (size_t)NI * 4;
    u16* BuT0 = (u16*)(ws + off); off += (size_t)ND * NU * 2;
    u16* BuT1 = (u16*)(ws + off); off += (size_t)ND * NU * 2;
    u16* BiT0 = (u16*)(ws + off); off += (size_t)ND * NI * 2;
    u16* BiT1 = (u16*)(ws + off); off += (size_t)ND * NI * 2;
    float* acc  = (float*)(ws + off); off += (size_t)NTOT * ND * 4;
    float* Ptop = (float*)(ws + off); off += (size_t)CT * NI * ND * 4; // 16 MiB
    float* Pbot = (float*)(ws + off); off += (size_t)CB * NU * ND * 4; // 16 MiB

    hipMemsetAsync(deg_u, 0, (NU + NI) * sizeof(int), stream);
    k_prep_pack<<<dim3(NI / 64, NU / 64), 256, 0, stream>>>(edge, Apk, ATpk, deg_u, deg_i);
    k_scale0<<<NTOT / 64, 256, 0, stream>>>(x, deg_u, deg_i, dsu, dsi, BuT0, BiT0);

    k_gemm_bit<<<2048, 256, 0, stream>>>(Apk, ATpk, BuT0, BiT0, Ptop, Pbot);
    k_reduce<<<NTOT / 64, 256, 0, stream>>>(Ptop, Pbot, dsu, dsi, acc, BuT1, BiT1, out, 0);
    k_gemm_bit<<<2048, 256, 0, stream>>>(Apk, ATpk, BuT1, BiT1, Ptop, Pbot);
    k_reduce<<<NTOT / 64, 256, 0, stream>>>(Ptop, Pbot, dsu, dsi, acc, BuT0, BiT0, out, 1);
    k_gemm_bit<<<2048, 256, 0, stream>>>(Apk, ATpk, BuT0, BiT0, Ptop, Pbot);
    k_reduce<<<NTOT / 64, 256, 0, stream>>>(Ptop, Pbot, dsu, dsi, acc,
                                            (u16*)nullptr, (u16*)nullptr, out, 2);
}

// Round 4
// 298.760 us; speedup vs baseline: 1.4002x; 1.4002x over previous
//
#include <hip/hip_runtime.h>

#define NU 4096
#define NI 8192
#define ND 64
#define NTOT 12288
#define CT 8           // top split-K chunks  (K=NU,  ck=512)
#define CB 16          // bottom split-K chunks (K=NI, ck=512)

typedef unsigned short u16;
typedef unsigned int u32;
typedef unsigned long long u64;

__device__ __forceinline__ u16 f2bf(float f) {
    union { float f; u32 u; } v; v.f = f;
    u32 u = v.u;
    u += 0x7FFFu + ((u >> 16) & 1u);   // round-to-nearest-even
    return (u16)(u >> 16);
}

typedef short frag8 __attribute__((ext_vector_type(8)));
typedef float f32x4 __attribute__((ext_vector_type(4)));

// ---------------------------------------------------------------------------
// K0: edge (int32 0/1) -> bit-packed A, NATURAL column order.
// Block = 64 rows x 512 cols. Loads: dword at col c4 + 16k so that
// ballot bit position == natural column offset. LDS-staged coalesced stores.
// ---------------------------------------------------------------------------
__global__ __launch_bounds__(256) void k_pack(const int* __restrict__ edge,
                                              u64* __restrict__ Apk) {
    __shared__ u64 wds[64][9];
    const int t = threadIdx.x, lane = t & 63, w = t >> 6;
    const int lg = lane >> 4, c4 = lane & 15;
    const int u0 = (blockIdx.x >> 4) * 64;
    const int i0 = (blockIdx.x & 15) * 512;
    const int q = (lane >> 2) & 3;     // producer's 16-bit slice

    #pragma unroll
    for (int m = 0; m < 8; m++) {
        u64 myw = 0;
        #pragma unroll
        for (int j = 0; j < 4; j++) {
            const size_t base = (size_t)(u0 + w * 16 + lg * 4 + j) * NI + i0 + m * 64 + c4;
            int v0 = edge[base];
            int v1 = edge[base + 16];
            int v2 = edge[base + 32];
            int v3 = edge[base + 48];
            u64 b0 = __ballot(v0 != 0);
            u64 b1 = __ballot(v1 != 0);
            u64 b2 = __ballot(v2 != 0);
            u64 b3 = __ballot(v3 != 0);
            u64 wd = ((b0 >> (16 * q)) & 0xFFFFULL)
                   | (((b1 >> (16 * q)) & 0xFFFFULL) << 16)
                   | (((b2 >> (16 * q)) & 0xFFFFULL) << 32)
                   | (((b3 >> (16 * q)) & 0xFFFFULL) << 48);
            if ((lane & 3) == j) myw = wd;   // producer lane l<16: row w*16+l
        }
        if (lane < 16) wds[w * 16 + lane][m] = myw;
    }
    __syncthreads();
    const int r = t >> 2, pr = t & 3;
    ulonglong2 w2;
    w2.x = wds[r][pr * 2];
    w2.y = wds[r][pr * 2 + 1];
    *(ulonglong2*)&Apk[(size_t)(u0 + r) * 128 + (i0 >> 6) + pr * 2] = w2;
}

// ---------------------------------------------------------------------------
// K1: 64x64 bit transpose of Apk -> ATpk via shfl_xor butterfly.
// Wave handles 8 stacked tiles (one Apk word-col g, 512 users) so the
// output per lane is 64 B contiguous.
// ---------------------------------------------------------------------------
__global__ __launch_bounds__(256) void k_bt(const u64* __restrict__ Apk,
                                            u64* __restrict__ ATpk) {
    const int t = threadIdx.x, lane = t & 63;
    const int wv = blockIdx.x * 4 + (t >> 6);
    const int g = wv >> 3;        // item group (word-col of Apk), 0..127
    const int us = wv & 7;        // user strip of 512, 0..7
    u64 x[8];
    #pragma unroll
    for (int tau = 0; tau < 8; tau++)
        x[tau] = Apk[(size_t)(us * 512 + tau * 64 + lane) * 128 + g];
    const u64 M[6] = {0x00000000FFFFFFFFULL, 0x0000FFFF0000FFFFULL,
                      0x00FF00FF00FF00FFULL, 0x0F0F0F0F0F0F0F0FULL,
                      0x3333333333333333ULL, 0x5555555555555555ULL};
    #pragma unroll
    for (int si = 0; si < 6; si++) {
        const int s = 32 >> si;
        #pragma unroll
        for (int tau = 0; tau < 8; tau++) {
            u64 y = __shfl_xor(x[tau], s, 64);
            x[tau] = (lane & s) ? ((x[tau] & ~M[si]) | ((y >> s) & M[si]))
                                : ((x[tau] &  M[si]) | ((y << s) & ~M[si]));
        }
    }
    #pragma unroll
    for (int qq = 0; qq < 4; qq++) {
        ulonglong2 w2; w2.x = x[2 * qq]; w2.y = x[2 * qq + 1];
        *(ulonglong2*)&ATpk[(size_t)(g * 64 + lane) * 64 + us * 8 + 2 * qq] = w2;
    }
}

// ---------------------------------------------------------------------------
// K2: degrees by popcount of packed rows + scale arrays + layer-0 B operands
// (embedding-major 64 x K). No atomics.
// ---------------------------------------------------------------------------
__global__ __launch_bounds__(256) void k_scale0(const float* __restrict__ x,
        const u64* __restrict__ Apk, const u64* __restrict__ ATpk,
        float* __restrict__ dsu, float* __restrict__ dsi,
        u16* __restrict__ BuT, u16* __restrict__ BiT) {
    __shared__ float sc[64];
    const int t = threadIdx.x;
    const int r0 = blockIdx.x * 64;
    {   // phase 1: degree of each of the 64 rows (4 threads per row)
        const int rl = t >> 2, part = t & 3;
        int cnt = 0;
        if (r0 < NU) {
            const u64* p = Apk + (size_t)(r0 + rl) * 128 + part * 32;
            #pragma unroll
            for (int i = 0; i < 32; i++) cnt += (int)__popcll(p[i]);
        } else {
            const u64* p = ATpk + (size_t)(r0 - NU + rl) * 64 + part * 16;
            #pragma unroll
            for (int i = 0; i < 16; i++) cnt += (int)__popcll(p[i]);
        }
        cnt += __shfl_xor(cnt, 1, 64);
        cnt += __shfl_xor(cnt, 2, 64);
        if (part == 0) {
            float s = cnt > 0 ? rsqrtf((float)cnt) : 0.f;
            sc[rl] = s;
            if (r0 < NU) dsu[r0 + rl] = s; else dsi[r0 - NU + rl] = s;
        }
    }
    __syncthreads();
    // phase 2: scaled bf16 operands, register 4x4 transpose
    const int r4 = t >> 4, c4 = t & 15;
    float y[4][4];
    #pragma unroll
    for (int j = 0; j < 4; j++) {
        const int rl = r4 * 4 + j;
        const float s = sc[rl];
        float4 xv = *(const float4*)(x + (size_t)(r0 + rl) * ND + c4 * 4);
        y[j][0] = xv.x * s; y[j][1] = xv.y * s;
        y[j][2] = xv.z * s; y[j][3] = xv.w * s;
    }
    u16* dst; size_t stride; int col0;
    if (r0 < NU) { dst = BuT; stride = NU; col0 = r0; }
    else         { dst = BiT; stride = NI; col0 = r0 - NU; }
    #pragma unroll
    for (int k = 0; k < 4; k++) {
        ushort4 w;
        w.x = f2bf(y[0][k]); w.y = f2bf(y[1][k]);
        w.z = f2bf(y[2][k]); w.w = f2bf(y[3][k]);
        *(ushort4*)(dst + (size_t)(c4 * 4 + k) * stride + col0 + r4 * 4) = w;
    }
}

// ---------------------------------------------------------------------------
// K3: split-K GEMM, operand-swapped: dense embeddings in the MFMA A-slot,
// adjacency bits (register-held) in the B-slot -> f32x4 coalesced stores.
// Dense chunk staged 64x64 per kk in XOR-swizzled LDS. 2048 blocks.
// ---------------------------------------------------------------------------
__global__ __launch_bounds__(256) void k_gemm(
        const u64* __restrict__ Apk, const u64* __restrict__ ATpk,
        const u16* __restrict__ BuT, const u16* __restrict__ BiT,
        float* __restrict__ Ptop, float* __restrict__ Pbot) {
    __shared__ u16 Bs[64][64];
    const int t = threadIdx.x, bx = blockIdx.x;
    const int lane = t & 63, w = t >> 6, lr = lane & 15, lg = lane >> 4;
    const u64* arow; const u16* dense; int Kstr, wpr, kbase; float* Pout;
    if (bx < 1024) {
        const int tile = bx >> 3, chunk = bx & 7;
        arow = ATpk + (size_t)(tile * 64) * 64 + chunk * 8; wpr = 64;
        dense = BuT; Kstr = NU; kbase = chunk * 512;
        Pout = Ptop + ((size_t)chunk * NI + tile * 64) * ND;
    } else {
        const int b2 = bx - 1024, tile = b2 >> 4, chunk = b2 & 15;
        arow = Apk + (size_t)(tile * 64) * 128 + chunk * 8; wpr = 128;
        dense = BiT; Kstr = NI; kbase = chunk * 512;
        Pout = Pbot + ((size_t)chunk * NU + tile * 64) * ND;
    }
    // preload this wave's 16 rows x 8 adjacency words (one row per lr lane)
    const u64* myrow = arow + (size_t)(w * 16 + lr) * wpr;
    u64 aw[8];
    #pragma unroll
    for (int qq = 0; qq < 4; qq++) {
        ulonglong2 v = *(const ulonglong2*)(myrow + qq * 2);
        aw[qq * 2] = v.x; aw[qq * 2 + 1] = v.y;
    }
    f32x4 acc[4];
    #pragma unroll
    for (int i = 0; i < 4; i++) acc[i] = f32x4{0.f, 0.f, 0.f, 0.f};
    const u16* gsrc = dense + kbase;

    for (int kk = 0; kk < 8; kk++) {
        __syncthreads();
        #pragma unroll
        for (int it = 0; it < 2; it++) {
            const int idx = t + it * 256;
            const int e = idx >> 3, seg = idx & 7;
            *(uint4*)&Bs[e][((seg ^ (e & 7)) * 8)] =
                *(const uint4*)(gsrc + (size_t)e * Kstr + kk * 64 + seg * 8);
        }
        __syncthreads();
        const u32 lo = (u32)aw[kk], hi = (u32)(aw[kk] >> 32);
        const u32 byte0 = (lo >> (lg * 8)) & 0xFFu;
        const u32 byte1 = (hi >> (lg * 8)) & 0xFFu;
        frag8 bf0, bf1;
        #pragma unroll
        for (int j = 0; j < 8; j++) {
            bf0[j] = (short)(((byte0 >> j) & 1u) ? 0x3F80 : 0);
            bf1[j] = (short)(((byte1 >> j) & 1u) ? 0x3F80 : 0);
        }
        #pragma unroll
        for (int nt = 0; nt < 4; nt++) {
            const int e = nt * 16 + lr, sw = e & 7;
            frag8 a0 = *(const frag8*)&Bs[e][(lg ^ sw) * 8];
            frag8 a1 = *(const frag8*)&Bs[e][((4 + lg) ^ sw) * 8];
            acc[nt] = __builtin_amdgcn_mfma_f32_16x16x32_bf16(a0, bf0, acc[nt], 0, 0, 0);
            acc[nt] = __builtin_amdgcn_mfma_f32_16x16x32_bf16(a1, bf1, acc[nt], 0, 0, 0);
        }
    }
    // D: col(lane&15)=output row, row(lg*4+reg)=embed -> f32x4 along embeds
    #pragma unroll
    for (int nt = 0; nt < 4; nt++)
        *(f32x4*)&Pout[(size_t)(w * 16 + lr) * ND + nt * 16 + lg * 4] = acc[nt];
}

// ---------------------------------------------------------------------------
// K4: reduce partials. 768 blocks x 16 rows; thread = one float4 of one row.
// Emits next-layer operands via LDS transpose (16-B stores).
// ---------------------------------------------------------------------------
__global__ __launch_bounds__(256) void k_reduce(
        const float* __restrict__ Ptop, const float* __restrict__ Pbot,
        const float* __restrict__ dsu, const float* __restrict__ dsi,
        float* __restrict__ accbuf, u16* __restrict__ BuTn,
        u16* __restrict__ BiTn, float* __restrict__ out, int layer) {
    __shared__ u16 TB[64][24];
    const int t = threadIdx.x, bx = blockIdx.x;
    const int rl = t >> 4, e4 = t & 15;
    int grow; float so;
    float sx = 0.f, sy = 0.f, sz = 0.f, sw = 0.f;
    if (bx < 512) {
        grow = bx * 16 + rl;
        const float* p = Ptop + (size_t)grow * ND + e4 * 4;
        #pragma unroll
        for (int c = 0; c < CT; c++) {
            float4 v = *(const float4*)(p + (size_t)c * NI * ND);
            sx += v.x; sy += v.y; sz += v.z; sw += v.w;
        }
        so = dsi[grow];
    } else {
        const int u = (bx - 512) * 16 + rl;
        grow = NI + u;
        const float* p = Pbot + (size_t)u * ND + e4 * 4;
        #pragma unroll
        for (int c = 0; c < CB; c++) {
            float4 v = *(const float4*)(p + (size_t)c * NU * ND);
            sx += v.x; sy += v.y; sz += v.z; sw += v.w;
        }
        so = dsu[grow - NI];
    }
    float4 y;
    y.x = sx * so; y.y = sy * so; y.z = sz * so; y.w = sw * so;
    const size_t o = (size_t)grow * ND + e4 * 4;
    if (layer == 0) {
        *(float4*)(accbuf + o) = y;
    } else if (layer == 1) {
        float4 a = *(const float4*)(accbuf + o);
        a.x += y.x; a.y += y.y; a.z += y.z; a.w += y.w;
        *(float4*)(accbuf + o) = a;
    } else {
        float4 a = *(const float4*)(accbuf + o);
        a.x = (a.x + y.x) * 0.25f; a.y = (a.y + y.y) * 0.25f;
        a.z = (a.z + y.z) * 0.25f; a.w = (a.w + y.w) * 0.25f;
        *(float4*)(out + o) = a;
    }
    if (layer != 2) {
        const float fn = (grow < NU) ? dsu[grow] : dsi[grow - NU];
        TB[e4 * 4 + 0][rl] = f2bf(y.x * fn);
        TB[e4 * 4 + 1][rl] = f2bf(y.y * fn);
        TB[e4 * 4 + 2][rl] = f2bf(y.z * fn);
        TB[e4 * 4 + 3][rl] = f2bf(y.w * fn);
        __syncthreads();
        if (t < 128) {
            const int e = t >> 1, h = t & 1;
            u16* dst; size_t stride; int col0;
            if (bx < 256)      { dst = BuTn; stride = NU; col0 = bx * 16; }
            else if (bx < 512) { dst = BiTn; stride = NI; col0 = bx * 16 - NU; }
            else               { dst = BiTn; stride = NI; col0 = (bx - 512) * 16 + NI - NU; }
            uint4 v = *(const uint4*)&TB[e][h * 8];
            *(uint4*)(dst + (size_t)e * stride + col0 + h * 8) = v;
        }
    }
}

extern "C" void kernel_launch(void* const* d_in, const int* in_sizes, int n_in,
                              void* d_out, int out_size, void* d_ws, size_t ws_size,
                              hipStream_t stream) {
    (void)in_sizes; (void)n_in; (void)out_size; (void)ws_size;
    const float* x    = (const float*)d_in[0];
    const int*   edge = (const int*)d_in[1];
    float* out = (float*)d_out;

    char* ws = (char*)d_ws;
    size_t off = 0;
    u64* Apk  = (u64*)(ws + off); off += (size_t)NU * (NI / 64) * 8;   // 4 MiB
    u64* ATpk = (u64*)(ws + off); off += (size_t)NI * (NU / 64) * 8;   // 4 MiB
    float* dsu = (float*)(ws + off); off += (size_t)NU * 4;
    float* dsi = (float*)(ws + off); off += (size_t)NI * 4;
    u16* BuT0 = (u16*)(ws + off); off += (size_t)ND * NU * 2;
    u16* BuT1 = (u16*)(ws + off); off += (size_t)ND * NU * 2;
    u16* BiT0 = (u16*)(ws + off); off += (size_t)ND * NI * 2;
    u16* BiT1 = (u16*)(ws + off); off += (size_t)ND * NI * 2;
    float* acc  = (float*)(ws + off); off += (size_t)NTOT * ND * 4;
    float* Ptop = (float*)(ws + off); off += (size_t)CT * NI * ND * 4; // 16 MiB
    float* Pbot = (float*)(ws + off); off += (size_t)CB * NU * ND * 4; // 16 MiB

    k_pack<<<1024, 256, 0, stream>>>(edge, Apk);
    k_bt<<<256, 256, 0, stream>>>(Apk, ATpk);
    k_scale0<<<NTOT / 64, 256, 0, stream>>>(x, Apk, ATpk, dsu, dsi, BuT0, BiT0);

    k_gemm<<<2048, 256, 0, stream>>>(Apk, ATpk, BuT0, BiT0, Ptop, Pbot);
    k_reduce<<<768, 256, 0, stream>>>(Ptop, Pbot, dsu, dsi, acc, BuT1, BiT1, out, 0);
    k_gemm<<<2048, 256, 0, stream>>>(Apk, ATpk, BuT1, BiT1, Ptop, Pbot);
    k_reduce<<<768, 256, 0, stream>>>(Ptop, Pbot, dsu, dsi, acc, BuT0, BiT0, out, 1);
    k_gemm<<<2048, 256, 0, stream>>>(Apk, ATpk, BuT0, BiT0, Ptop, Pbot);
    k_reduce<<<768, 256, 0, stream>>>(Ptop, Pbot, dsu, dsi, acc,
                                      (u16*)nullptr, (u16*)nullptr, out, 2);
}

// Round 5
// 293.675 us; speedup vs baseline: 1.4245x; 1.0173x over previous
//
#include <hip/hip_runtime.h>

#define NU 4096
#define NI 8192
#define ND 64
#define NTOT 12288
#define CT 8           // top split-K chunks  (K=NU,  ck=512)
#define CB 16          // bottom split-K chunks (K=NI, ck=512)

typedef unsigned short u16;
typedef unsigned int u32;
typedef unsigned long long u64;

__device__ __forceinline__ u16 f2bf(float f) {
    union { float f; u32 u; } v; v.f = f;
    u32 u = v.u;
    u += 0x7FFFu + ((u >> 16) & 1u);   // round-to-nearest-even
    return (u16)(u >> 16);
}

typedef short frag8 __attribute__((ext_vector_type(8)));
typedef float f32x4 __attribute__((ext_vector_type(4)));

// ---------------------------------------------------------------------------
// K0: edge (int32 0/1) -> bit-packed A AND AT in one pass. Block = 256 rows
// x 512 cols. int4 loads (64 B/lane runs), lane-local 16-bit pack, LDS
// assemble, full-line Apk stores; in-LDS 64x64 shfl-butterfly for AT.
// ---------------------------------------------------------------------------
__global__ __launch_bounds__(256) void k_pack2(const int* __restrict__ edge,
        u64* __restrict__ Apk, u64* __restrict__ ATpk) {
    __shared__ __align__(16) u16 At[256][40];   // packed row bits (pad: 80 B rows)
    __shared__ __align__(16) u64 Tt[512][6];    // AT staging (48 B rows)
    const int t = threadIdx.x;
    const int u0 = (blockIdx.x >> 4) * 256;
    const int i0 = (blockIdx.x & 15) * 512;
    const int cg = t & 31;          // 16-col group
    const int rb = t >> 5;          // row base (32 rows each)

    #pragma unroll 4
    for (int rr = 0; rr < 32; rr++) {
        const int row = rb * 32 + rr;
        const int4* p = (const int4*)(edge + (size_t)(u0 + row) * NI + i0 + cg * 16);
        u32 bits = 0;
        #pragma unroll
        for (int m = 0; m < 4; m++) {
            int4 v = p[m];
            bits |= (v.x != 0 ? 1u : 0u) << (m * 4 + 0);
            bits |= (v.y != 0 ? 1u : 0u) << (m * 4 + 1);
            bits |= (v.z != 0 ? 1u : 0u) << (m * 4 + 2);
            bits |= (v.w != 0 ? 1u : 0u) << (m * 4 + 3);
        }
        At[row][cg] = (u16)bits;
    }
    __syncthreads();

    // Apk: thread t = row t; 64 B contiguous per lane -> full-line stores
    {
        u64* dst = Apk + (size_t)(u0 + t) * 128 + (i0 >> 6);
        #pragma unroll
        for (int q = 0; q < 4; q++) {
            uint4 v = *(const uint4*)&At[t][q * 8];
            *(uint4*)(dst + q * 2) = v;
        }
    }

    // AT: butterfly-transpose 64x64 bit subtiles; wave w = user strip
    {
        const int lane = t & 63, w = t >> 6;
        const u64 M[6] = {0x00000000FFFFFFFFULL, 0x0000FFFF0000FFFFULL,
                          0x00FF00FF00FF00FFULL, 0x0F0F0F0F0F0F0F0FULL,
                          0x3333333333333333ULL, 0x5555555555555555ULL};
        #pragma unroll
        for (int sc = 0; sc < 8; sc++) {
            u64 x = *(const u64*)&At[w * 64 + lane][sc * 4];
            #pragma unroll
            for (int si = 0; si < 6; si++) {
                const int s = 32 >> si;
                u64 y = __shfl_xor(x, s, 64);
                x = (lane & s) ? ((x & ~M[si]) | ((y >> s) & M[si]))
                               : ((x &  M[si]) | ((y << s) & ~M[si]));
            }
            Tt[sc * 64 + lane][w] = x;
        }
    }
    __syncthreads();
    #pragma unroll
    for (int j = 0; j < 2; j++) {
        const int item = t * 2 + j;
        ulonglong2 a = *(const ulonglong2*)&Tt[item][0];
        ulonglong2 b = *(const ulonglong2*)&Tt[item][2];
        u64* dst = ATpk + (size_t)(i0 + item) * 64 + (u0 >> 6);
        *(ulonglong2*)dst = a;
        *(ulonglong2*)(dst + 2) = b;
    }
}

// ---------------------------------------------------------------------------
// K1: degrees by popcount of packed rows + scale arrays + layer-0 B operands
// (embedding-major 64 x K). No atomics.
// ---------------------------------------------------------------------------
__global__ __launch_bounds__(256) void k_scale0(const float* __restrict__ x,
        const u64* __restrict__ Apk, const u64* __restrict__ ATpk,
        float* __restrict__ dsu, float* __restrict__ dsi,
        u16* __restrict__ BuT, u16* __restrict__ BiT) {
    __shared__ float sc[64];
    const int t = threadIdx.x;
    const int r0 = blockIdx.x * 64;
    {
        const int rl = t >> 2, part = t & 3;
        int cnt = 0;
        if (r0 < NU) {
            const u64* p = Apk + (size_t)(r0 + rl) * 128 + part * 32;
            #pragma unroll
            for (int i = 0; i < 32; i++) cnt += (int)__popcll(p[i]);
        } else {
            const u64* p = ATpk + (size_t)(r0 - NU + rl) * 64 + part * 16;
            #pragma unroll
            for (int i = 0; i < 16; i++) cnt += (int)__popcll(p[i]);
        }
        cnt += __shfl_xor(cnt, 1, 64);
        cnt += __shfl_xor(cnt, 2, 64);
        if (part == 0) {
            float s = cnt > 0 ? rsqrtf((float)cnt) : 0.f;
            sc[rl] = s;
            if (r0 < NU) dsu[r0 + rl] = s; else dsi[r0 - NU + rl] = s;
        }
    }
    __syncthreads();
    const int r4 = t >> 4, c4 = t & 15;
    float y[4][4];
    #pragma unroll
    for (int j = 0; j < 4; j++) {
        const int rl = r4 * 4 + j;
        const float s = sc[rl];
        float4 xv = *(const float4*)(x + (size_t)(r0 + rl) * ND + c4 * 4);
        y[j][0] = xv.x * s; y[j][1] = xv.y * s;
        y[j][2] = xv.z * s; y[j][3] = xv.w * s;
    }
    u16* dst; size_t stride; int col0;
    if (r0 < NU) { dst = BuT; stride = NU; col0 = r0; }
    else         { dst = BiT; stride = NI; col0 = r0 - NU; }
    #pragma unroll
    for (int k = 0; k < 4; k++) {
        ushort4 w;
        w.x = f2bf(y[0][k]); w.y = f2bf(y[1][k]);
        w.z = f2bf(y[2][k]); w.w = f2bf(y[3][k]);
        *(ushort4*)(dst + (size_t)(c4 * 4 + k) * stride + col0 + r4 * 4) = w;
    }
}

// ---------------------------------------------------------------------------
// K2: split-K GEMM. Full 64x512 dense chunk staged ONCE in 64 KB LDS
// (one barrier pair), then 8 barrier-free kk steps of LDS+MFMA.
// Dense embeddings in the MFMA A-slot, register-held adjacency bits in the
// B-slot -> f32x4 coalesced partial stores. 2048 blocks.
// ---------------------------------------------------------------------------
__global__ __launch_bounds__(256) void k_gemm(
        const u64* __restrict__ Apk, const u64* __restrict__ ATpk,
        const u16* __restrict__ BuT, const u16* __restrict__ BiT,
        float* __restrict__ Ptop, float* __restrict__ Pbot) {
    __shared__ __align__(16) u16 Bs[64][512];   // 64 KB, XOR-swizzled per 64-col group
    const int t = threadIdx.x, bx = blockIdx.x;
    const int lane = t & 63, w = t >> 6, lr = lane & 15, lg = lane >> 4;
    const u64* arow; const u16* dense; int Kstr, wpr, kbase; float* Pout;
    if (bx < 1024) {
        const int tile = bx >> 3, chunk = bx & 7;
        arow = ATpk + (size_t)(tile * 64) * 64 + chunk * 8; wpr = 64;
        dense = BuT; Kstr = NU; kbase = chunk * 512;
        Pout = Ptop + ((size_t)chunk * NI + tile * 64) * ND;
    } else {
        const int b2 = bx - 1024, tile = b2 >> 4, chunk = b2 & 15;
        arow = Apk + (size_t)(tile * 64) * 128 + chunk * 8; wpr = 128;
        dense = BiT; Kstr = NI; kbase = chunk * 512;
        Pout = Pbot + ((size_t)chunk * NU + tile * 64) * ND;
    }
    // preload this wave's 16 rows x 8 adjacency words (one row per lr lane)
    const u64* myrow = arow + (size_t)(w * 16 + lr) * wpr;
    u64 aw[8];
    #pragma unroll
    for (int qq = 0; qq < 4; qq++) {
        ulonglong2 v = *(const ulonglong2*)(myrow + qq * 2);
        aw[qq * 2] = v.x; aw[qq * 2 + 1] = v.y;
    }
    // stage the full 64x512 dense chunk (one row per wave-instruction)
    const u16* gsrc = dense + kbase;
    #pragma unroll
    for (int it = 0; it < 16; it++) {
        const int idx = t + it * 256;
        const int e = idx >> 6, seg = idx & 63;
        const int kk = seg >> 3, s8 = seg & 7;
        *(uint4*)&Bs[e][kk * 64 + ((s8 ^ (e & 7)) * 8)] =
            *(const uint4*)(gsrc + (size_t)e * Kstr + seg * 8);
    }
    f32x4 acc[4];
    #pragma unroll
    for (int i = 0; i < 4; i++) acc[i] = f32x4{0.f, 0.f, 0.f, 0.f};
    __syncthreads();

    #pragma unroll
    for (int kk = 0; kk < 8; kk++) {
        const u32 lo = (u32)aw[kk], hi = (u32)(aw[kk] >> 32);
        const u32 byte0 = (lo >> (lg * 8)) & 0xFFu;
        const u32 byte1 = (hi >> (lg * 8)) & 0xFFu;
        frag8 bf0, bf1;
        #pragma unroll
        for (int j = 0; j < 8; j++) {
            bf0[j] = (short)(((byte0 >> j) & 1u) ? 0x3F80 : 0);
            bf1[j] = (short)(((byte1 >> j) & 1u) ? 0x3F80 : 0);
        }
        #pragma unroll
        for (int nt = 0; nt < 4; nt++) {
            const int e = nt * 16 + lr, sw = e & 7;
            frag8 a0 = *(const frag8*)&Bs[e][kk * 64 + ((lg ^ sw) * 8)];
            frag8 a1 = *(const frag8*)&Bs[e][kk * 64 + (((4 + lg) ^ sw) * 8)];
            acc[nt] = __builtin_amdgcn_mfma_f32_16x16x32_bf16(a0, bf0, acc[nt], 0, 0, 0);
            acc[nt] = __builtin_amdgcn_mfma_f32_16x16x32_bf16(a1, bf1, acc[nt], 0, 0, 0);
        }
    }
    // D: col(lane&15)=output row, row(lg*4+reg)=embed -> f32x4 along embeds
    #pragma unroll
    for (int nt = 0; nt < 4; nt++)
        *(f32x4*)&Pout[(size_t)(w * 16 + lr) * ND + nt * 16 + lg * 4] = acc[nt];
}

// ---------------------------------------------------------------------------
// K3: reduce partials. 768 blocks x 16 rows; thread = one float4 of one row.
// Emits next-layer operands via LDS transpose (16-B stores).
// ---------------------------------------------------------------------------
__global__ __launch_bounds__(256) void k_reduce(
        const float* __restrict__ Ptop, const float* __restrict__ Pbot,
        const float* __restrict__ dsu, const float* __restrict__ dsi,
        float* __restrict__ accbuf, u16* __restrict__ BuTn,
        u16* __restrict__ BiTn, float* __restrict__ out, int layer) {
    __shared__ u16 TB[64][24];
    const int t = threadIdx.x, bx = blockIdx.x;
    const int rl = t >> 4, e4 = t & 15;
    int grow; float so;
    float sx = 0.f, sy = 0.f, sz = 0.f, sw = 0.f;
    if (bx < 512) {
        grow = bx * 16 + rl;
        const float* p = Ptop + (size_t)grow * ND + e4 * 4;
        #pragma unroll
        for (int c = 0; c < CT; c++) {
            float4 v = *(const float4*)(p + (size_t)c * NI * ND);
            sx += v.x; sy += v.y; sz += v.z; sw += v.w;
        }
        so = dsi[grow];
    } else {
        const int u = (bx - 512) * 16 + rl;
        grow = NI + u;
        const float* p = Pbot + (size_t)u * ND + e4 * 4;
        #pragma unroll
        for (int c = 0; c < CB; c++) {
            float4 v = *(const float4*)(p + (size_t)c * NU * ND);
            sx += v.x; sy += v.y; sz += v.z; sw += v.w;
        }
        so = dsu[grow - NI];
    }
    float4 y;
    y.x = sx * so; y.y = sy * so; y.z = sz * so; y.w = sw * so;
    const size_t o = (size_t)grow * ND + e4 * 4;
    if (layer == 0) {
        *(float4*)(accbuf + o) = y;
    } else if (layer == 1) {
        float4 a = *(const float4*)(accbuf + o);
        a.x += y.x; a.y += y.y; a.z += y.z; a.w += y.w;
        *(float4*)(accbuf + o) = a;
    } else {
        float4 a = *(const float4*)(accbuf + o);
        a.x = (a.x + y.x) * 0.25f; a.y = (a.y + y.y) * 0.25f;
        a.z = (a.z + y.z) * 0.25f; a.w = (a.w + y.w) * 0.25f;
        *(float4*)(out + o) = a;
    }
    if (layer != 2) {
        const float fn = (grow < NU) ? dsu[grow] : dsi[grow - NU];
        TB[e4 * 4 + 0][rl] = f2bf(y.x * fn);
        TB[e4 * 4 + 1][rl] = f2bf(y.y * fn);
        TB[e4 * 4 + 2][rl] = f2bf(y.z * fn);
        TB[e4 * 4 + 3][rl] = f2bf(y.w * fn);
        __syncthreads();
        if (t < 128) {
            const int e = t >> 1, h = t & 1;
            u16* dst; size_t stride; int col0;
            if (bx < 256)      { dst = BuTn; stride = NU; col0 = bx * 16; }
            else if (bx < 512) { dst = BiTn; stride = NI; col0 = bx * 16 - NU; }
            else               { dst = BiTn; stride = NI; col0 = (bx - 512) * 16 + NI - NU; }
            uint4 v = *(const uint4*)&TB[e][h * 8];
            *(uint4*)(dst + (size_t)e * stride + col0 + h * 8) = v;
        }
    }
}

extern "C" void kernel_launch(void* const* d_in, const int* in_sizes, int n_in,
                              void* d_out, int out_size, void* d_ws, size_t ws_size,
                              hipStream_t stream) {
    (void)in_sizes; (void)n_in; (void)out_size; (void)ws_size;
    const float* x    = (const float*)d_in[0];
    const int*   edge = (const int*)d_in[1];
    float* out = (float*)d_out;

    char* ws = (char*)d_ws;
    size_t off = 0;
    u64* Apk  = (u64*)(ws + off); off += (size_t)NU * (NI / 64) * 8;   // 4 MiB
    u64* ATpk = (u64*)(ws + off); off += (size_t)NI * (NU / 64) * 8;   // 4 MiB
    float* dsu = (float*)(ws + off); off += (size_t)NU * 4;
    float* dsi = (float*)(ws + off); off += (size_t)NI * 4;
    u16* BuT0 = (u16*)(ws + off); off += (size_t)ND * NU * 2;
    u16* BuT1 = (u16*)(ws + off); off += (size_t)ND * NU * 2;
    u16* BiT0 = (u16*)(ws + off); off += (size_t)ND * NI * 2;
    u16* BiT1 = (u16*)(ws + off); off += (size_t)ND * NI * 2;
    float* acc  = (float*)(ws + off); off += (size_t)NTOT * ND * 4;
    float* Ptop = (float*)(ws + off); off += (size_t)CT * NI * ND * 4; // 16 MiB
    float* Pbot = (float*)(ws + off); off += (size_t)CB * NU * ND * 4; // 16 MiB

    k_pack2<<<256, 256, 0, stream>>>(edge, Apk, ATpk);
    k_scale0<<<NTOT / 64, 256, 0, stream>>>(x, Apk, ATpk, dsu, dsi, BuT0, BiT0);

    k_gemm<<<2048, 256, 0, stream>>>(Apk, ATpk, BuT0, BiT0, Ptop, Pbot);
    k_reduce<<<768, 256, 0, stream>>>(Ptop, Pbot, dsu, dsi, acc, BuT1, BiT1, out, 0);
    k_gemm<<<2048, 256, 0, stream>>>(Apk, ATpk, BuT1, BiT1, Ptop, Pbot);
    k_reduce<<<768, 256, 0, stream>>>(Ptop, Pbot, dsu, dsi, acc, BuT0, BiT0, out, 1);
    k_gemm<<<2048, 256, 0, stream>>>(Apk, ATpk, BuT0, BiT0, Ptop, Pbot);
    k_reduce<<<768, 256, 0, stream>>>(Ptop, Pbot, dsu, dsi, acc,
                                      (u16*)nullptr, (u16*)nullptr, out, 2);
}

// Round 6
// 287.941 us; speedup vs baseline: 1.4528x; 1.0199x over previous
//
#include <hip/hip_runtime.h>

#define NU 4096
#define NI 8192
#define ND 64
#define NTOT 12288
#define CT 8           // top split-K chunks  (K=NU,  ck=512)
#define CB 16          // bottom split-K chunks (K=NI, ck=512)
#define BROW 520       // u16 per staged dense row (512 + 8 pad -> even LDS spread)

typedef unsigned short u16;
typedef unsigned int u32;
typedef unsigned long long u64;

__device__ __forceinline__ u16 f2bf(float f) {
    union { float f; u32 u; } v; v.f = f;
    u32 u = v.u;
    u += 0x7FFFu + ((u >> 16) & 1u);   // round-to-nearest-even
    return (u16)(u >> 16);
}

typedef short frag8 __attribute__((ext_vector_type(8)));
typedef float f32x4 __attribute__((ext_vector_type(4)));

// ---------------------------------------------------------------------------
// K0: edge (int32 0/1) -> bit-packed A AND AT in one pass. Block = 256 rows
// x 512 cols. int4 loads, lane-local 16-bit pack, LDS assemble, full-line
// Apk stores; in-LDS 64x64 shfl-butterfly for AT.
// ---------------------------------------------------------------------------
__global__ __launch_bounds__(256) void k_pack2(const int* __restrict__ edge,
        u64* __restrict__ Apk, u64* __restrict__ ATpk) {
    __shared__ __align__(16) u16 At[256][40];
    __shared__ __align__(16) u64 Tt[512][6];
    const int t = threadIdx.x;
    const int u0 = (blockIdx.x >> 4) * 256;
    const int i0 = (blockIdx.x & 15) * 512;
    const int cg = t & 31;
    const int rb = t >> 5;

    #pragma unroll 4
    for (int rr = 0; rr < 32; rr++) {
        const int row = rb * 32 + rr;
        const int4* p = (const int4*)(edge + (size_t)(u0 + row) * NI + i0 + cg * 16);
        u32 bits = 0;
        #pragma unroll
        for (int m = 0; m < 4; m++) {
            int4 v = p[m];
            bits |= (v.x != 0 ? 1u : 0u) << (m * 4 + 0);
            bits |= (v.y != 0 ? 1u : 0u) << (m * 4 + 1);
            bits |= (v.z != 0 ? 1u : 0u) << (m * 4 + 2);
            bits |= (v.w != 0 ? 1u : 0u) << (m * 4 + 3);
        }
        At[row][cg] = (u16)bits;
    }
    __syncthreads();

    {
        u64* dst = Apk + (size_t)(u0 + t) * 128 + (i0 >> 6);
        #pragma unroll
        for (int q = 0; q < 4; q++) {
            uint4 v = *(const uint4*)&At[t][q * 8];
            *(uint4*)(dst + q * 2) = v;
        }
    }

    {
        const int lane = t & 63, w = t >> 6;
        const u64 M[6] = {0x00000000FFFFFFFFULL, 0x0000FFFF0000FFFFULL,
                          0x00FF00FF00FF00FFULL, 0x0F0F0F0F0F0F0F0FULL,
                          0x3333333333333333ULL, 0x5555555555555555ULL};
        #pragma unroll
        for (int sc = 0; sc < 8; sc++) {
            u64 x = *(const u64*)&At[w * 64 + lane][sc * 4];
            #pragma unroll
            for (int si = 0; si < 6; si++) {
                const int s = 32 >> si;
                u64 y = __shfl_xor(x, s, 64);
                x = (lane & s) ? ((x & ~M[si]) | ((y >> s) & M[si]))
                               : ((x &  M[si]) | ((y << s) & ~M[si]));
            }
            Tt[sc * 64 + lane][w] = x;
        }
    }
    __syncthreads();
    #pragma unroll
    for (int j = 0; j < 2; j++) {
        const int item = t * 2 + j;
        ulonglong2 a = *(const ulonglong2*)&Tt[item][0];
        ulonglong2 b = *(const ulonglong2*)&Tt[item][2];
        u64* dst = ATpk + (size_t)(i0 + item) * 64 + (u0 >> 6);
        *(ulonglong2*)dst = a;
        *(ulonglong2*)(dst + 2) = b;
    }
}

// ---------------------------------------------------------------------------
// K1: degrees by popcount of packed rows + scale arrays + layer-0 B operands
// (embedding-major 64 x K). No atomics.
// ---------------------------------------------------------------------------
__global__ __launch_bounds__(256) void k_scale0(const float* __restrict__ x,
        const u64* __restrict__ Apk, const u64* __restrict__ ATpk,
        float* __restrict__ dsu, float* __restrict__ dsi,
        u16* __restrict__ BuT, u16* __restrict__ BiT) {
    __shared__ float sc[64];
    const int t = threadIdx.x;
    const int r0 = blockIdx.x * 64;
    {
        const int rl = t >> 2, part = t & 3;
        int cnt = 0;
        if (r0 < NU) {
            const u64* p = Apk + (size_t)(r0 + rl) * 128 + part * 32;
            #pragma unroll
            for (int i = 0; i < 32; i++) cnt += (int)__popcll(p[i]);
        } else {
            const u64* p = ATpk + (size_t)(r0 - NU + rl) * 64 + part * 16;
            #pragma unroll
            for (int i = 0; i < 16; i++) cnt += (int)__popcll(p[i]);
        }
        cnt += __shfl_xor(cnt, 1, 64);
        cnt += __shfl_xor(cnt, 2, 64);
        if (part == 0) {
            float s = cnt > 0 ? rsqrtf((float)cnt) : 0.f;
            sc[rl] = s;
            if (r0 < NU) dsu[r0 + rl] = s; else dsi[r0 - NU + rl] = s;
        }
    }
    __syncthreads();
    const int r4 = t >> 4, c4 = t & 15;
    float y[4][4];
    #pragma unroll
    for (int j = 0; j < 4; j++) {
        const int rl = r4 * 4 + j;
        const float s = sc[rl];
        float4 xv = *(const float4*)(x + (size_t)(r0 + rl) * ND + c4 * 4);
        y[j][0] = xv.x * s; y[j][1] = xv.y * s;
        y[j][2] = xv.z * s; y[j][3] = xv.w * s;
    }
    u16* dst; size_t stride; int col0;
    if (r0 < NU) { dst = BuT; stride = NU; col0 = r0; }
    else         { dst = BiT; stride = NI; col0 = r0 - NU; }
    #pragma unroll
    for (int k = 0; k < 4; k++) {
        ushort4 w;
        w.x = f2bf(y[0][k]); w.y = f2bf(y[1][k]);
        w.z = f2bf(y[2][k]); w.w = f2bf(y[3][k]);
        *(ushort4*)(dst + (size_t)(c4 * 4 + k) * stride + col0 + r4 * 4) = w;
    }
}

// ---------------------------------------------------------------------------
// K2: split-K GEMM. global_load_lds width-16 staging into 1040-B rows,
// one barrier pair; 8 barrier-free kk steps. Epilogue: LDS-stash the
// accumulator tile (rotation-staggered) -> 1KB-contiguous partial stores
// into chunk-MINOR layout P[row][chunk][64].
// ---------------------------------------------------------------------------
__global__ __launch_bounds__(256) void k_gemm(
        const u64* __restrict__ Apk, const u64* __restrict__ ATpk,
        const u16* __restrict__ BuT, const u16* __restrict__ BiT,
        float* __restrict__ Ptop, float* __restrict__ Pbot) {
    __shared__ __align__(16) u16 Bs[64 * BROW];   // 66.6 KB
    const int t = threadIdx.x, bx = blockIdx.x;
    const int lane = t & 63, w = t >> 6, lr = lane & 15, lg = lane >> 4;
    const u64* arow; const u16* dense; int Kstr, wpr, kbase, pstr; float* Pout;
    if (bx < 1024) {
        const int tile = bx >> 3, chunk = bx & 7;
        arow = ATpk + (size_t)(tile * 64) * 64 + chunk * 8; wpr = 64;
        dense = BuT; Kstr = NU; kbase = chunk * 512; pstr = CT * 64;
        Pout = Ptop + (size_t)(tile * 64) * pstr + chunk * 64;
    } else {
        const int b2 = bx - 1024, tile = b2 >> 4, chunk = b2 & 15;
        arow = Apk + (size_t)(tile * 64) * 128 + chunk * 8; wpr = 128;
        dense = BiT; Kstr = NI; kbase = chunk * 512; pstr = CB * 64;
        Pout = Pbot + (size_t)(tile * 64) * pstr + chunk * 64;
    }
    // stage the full 64x512 dense chunk: wave-level DMA, 1 KB per inst
    const u16* gsrc = dense + kbase;
    #pragma unroll
    for (int it = 0; it < 16; it++) {
        const int e = it * 4 + w;   // wave-uniform row
        __builtin_amdgcn_global_load_lds(
            (const __attribute__((address_space(1))) void*)
                (gsrc + (size_t)e * Kstr + lane * 8),
            (__attribute__((address_space(3))) void*)(&Bs[e * BROW]),
            16, 0, 0);
    }
    // preload this wave's 16 rows x 8 adjacency words
    const u64* myrow = arow + (size_t)(w * 16 + lr) * wpr;
    u64 aw[8];
    #pragma unroll
    for (int qq = 0; qq < 4; qq++) {
        ulonglong2 v = *(const ulonglong2*)(myrow + qq * 2);
        aw[qq * 2] = v.x; aw[qq * 2 + 1] = v.y;
    }
    f32x4 acc[4];
    #pragma unroll
    for (int i = 0; i < 4; i++) acc[i] = f32x4{0.f, 0.f, 0.f, 0.f};
    __syncthreads();

    #pragma unroll
    for (int kk = 0; kk < 8; kk++) {
        const u32 lo = (u32)aw[kk], hi = (u32)(aw[kk] >> 32);
        const u32 byte0 = (lo >> (lg * 8)) & 0xFFu;
        const u32 byte1 = (hi >> (lg * 8)) & 0xFFu;
        frag8 bf0, bf1;
        #pragma unroll
        for (int j = 0; j < 8; j++) {
            bf0[j] = (short)(((byte0 >> j) & 1u) ? 0x3F80 : 0);
            bf1[j] = (short)(((byte1 >> j) & 1u) ? 0x3F80 : 0);
        }
        #pragma unroll
        for (int nt = 0; nt < 4; nt++) {
            const int e = nt * 16 + lr;
            frag8 a0 = *(const frag8*)&Bs[e * BROW + kk * 64 + lg * 8];
            frag8 a1 = *(const frag8*)&Bs[e * BROW + kk * 64 + 32 + lg * 8];
            acc[nt] = __builtin_amdgcn_mfma_f32_16x16x32_bf16(a0, bf0, acc[nt], 0, 0, 0);
            acc[nt] = __builtin_amdgcn_mfma_f32_16x16x32_bf16(a1, bf1, acc[nt], 0, 0, 0);
        }
    }
    // stash tile in LDS (rotation-staggered granules), then coalesced stores
    __syncthreads();                      // all Bs reads done
    float* Fs = (float*)Bs;               // 64 rows x 16 granules x 4 floats
    #pragma unroll
    for (int nt = 0; nt < 4; nt++) {
        const int row = w * 16 + lr, g = nt * 4 + lg;
        *(f32x4*)&Fs[row * 64 + (((g + row) & 15) * 4)] = acc[nt];
    }
    __syncthreads();
    #pragma unroll
    for (int ii = 0; ii < 4; ii++) {
        const int slot = t + ii * 256;
        const int row = slot >> 4, g = slot & 15;
        f32x4 v = *(const f32x4*)&Fs[row * 64 + (((g + row) & 15) * 4)];
        *(f32x4*)&Pout[(size_t)row * pstr + g * 4] = v;
    }
}

// ---------------------------------------------------------------------------
// K3: reduce partials (chunk-minor layout: per-row data fully contiguous),
// apply output scale, acc/out logic, emit next-layer B operands.
// ---------------------------------------------------------------------------
__global__ __launch_bounds__(256) void k_reduce(
        const float* __restrict__ Ptop, const float* __restrict__ Pbot,
        const float* __restrict__ dsu, const float* __restrict__ dsi,
        float* __restrict__ accbuf, u16* __restrict__ BuTn,
        u16* __restrict__ BiTn, float* __restrict__ out, int layer) {
    __shared__ u16 TB[64][24];
    const int t = threadIdx.x, bx = blockIdx.x;
    const int rl = t >> 4, e4 = t & 15;
    int grow; float so;
    float sx = 0.f, sy = 0.f, sz = 0.f, sw = 0.f;
    if (bx < 512) {
        grow = bx * 16 + rl;
        const float* p = Ptop + (size_t)grow * (CT * 64) + e4 * 4;
        #pragma unroll
        for (int c = 0; c < CT; c++) {
            float4 v = *(const float4*)(p + c * 64);
            sx += v.x; sy += v.y; sz += v.z; sw += v.w;
        }
        so = dsi[grow];
    } else {
        const int u = (bx - 512) * 16 + rl;
        grow = NI + u;
        const float* p = Pbot + (size_t)u * (CB * 64) + e4 * 4;
        #pragma unroll
        for (int c = 0; c < CB; c++) {
            float4 v = *(const float4*)(p + c * 64);
            sx += v.x; sy += v.y; sz += v.z; sw += v.w;
        }
        so = dsu[grow - NI];
    }
    float4 y;
    y.x = sx * so; y.y = sy * so; y.z = sz * so; y.w = sw * so;
    const size_t o = (size_t)grow * ND + e4 * 4;
    if (layer == 0) {
        *(float4*)(accbuf + o) = y;
    } else if (layer == 1) {
        float4 a = *(const float4*)(accbuf + o);
        a.x += y.x; a.y += y.y; a.z += y.z; a.w += y.w;
        *(float4*)(accbuf + o) = a;
    } else {
        float4 a = *(const float4*)(accbuf + o);
        a.x = (a.x + y.x) * 0.25f; a.y = (a.y + y.y) * 0.25f;
        a.z = (a.z + y.z) * 0.25f; a.w = (a.w + y.w) * 0.25f;
        *(float4*)(out + o) = a;
    }
    if (layer != 2) {
        const float fn = (grow < NU) ? dsu[grow] : dsi[grow - NU];
        TB[e4 * 4 + 0][rl] = f2bf(y.x * fn);
        TB[e4 * 4 + 1][rl] = f2bf(y.y * fn);
        TB[e4 * 4 + 2][rl] = f2bf(y.z * fn);
        TB[e4 * 4 + 3][rl] = f2bf(y.w * fn);
        __syncthreads();
        if (t < 128) {
            const int e = t >> 1, h = t & 1;
            u16* dst; size_t stride; int col0;
            if (bx < 256)      { dst = BuTn; stride = NU; col0 = bx * 16; }
            else if (bx < 512) { dst = BiTn; stride = NI; col0 = bx * 16 - NU; }
            else               { dst = BiTn; stride = NI; col0 = (bx - 512) * 16 + NI - NU; }
            uint4 v = *(const uint4*)&TB[e][h * 8];
            *(uint4*)(dst + (size_t)e * stride + col0 + h * 8) = v;
        }
    }
}

extern "C" void kernel_launch(void* const* d_in, const int* in_sizes, int n_in,
                              void* d_out, int out_size, void* d_ws, size_t ws_size,
                              hipStream_t stream) {
    (void)in_sizes; (void)n_in; (void)out_size; (void)ws_size;
    const float* x    = (const float*)d_in[0];
    const int*   edge = (const int*)d_in[1];
    float* out = (float*)d_out;

    char* ws = (char*)d_ws;
    size_t off = 0;
    u64* Apk  = (u64*)(ws + off); off += (size_t)NU * (NI / 64) * 8;   // 4 MiB
    u64* ATpk = (u64*)(ws + off); off += (size_t)NI * (NU / 64) * 8;   // 4 MiB
    float* dsu = (float*)(ws + off); off += (size_t)NU * 4;
    float* dsi = (float*)(ws + off); off += (size_t)NI * 4;
    u16* BuT0 = (u16*)(ws + off); off += (size_t)ND * NU * 2;
    u16* BuT1 = (u16*)(ws + off); off += (size_t)ND * NU * 2;
    u16* BiT0 = (u16*)(ws + off); off += (size_t)ND * NI * 2;
    u16* BiT1 = (u16*)(ws + off); off += (size_t)ND * NI * 2;
    float* acc  = (float*)(ws + off); off += (size_t)NTOT * ND * 4;
    float* Ptop = (float*)(ws + off); off += (size_t)NI * CT * 64 * 4; // 16 MiB
    float* Pbot = (float*)(ws + off); off += (size_t)NU * CB * 64 * 4; // 16 MiB

    k_pack2<<<256, 256, 0, stream>>>(edge, Apk, ATpk);
    k_scale0<<<NTOT / 64, 256, 0, stream>>>(x, Apk, ATpk, dsu, dsi, BuT0, BiT0);

    k_gemm<<<2048, 256, 0, stream>>>(Apk, ATpk, BuT0, BiT0, Ptop, Pbot);
    k_reduce<<<768, 256, 0, stream>>>(Ptop, Pbot, dsu, dsi, acc, BuT1, BiT1, out, 0);
    k_gemm<<<2048, 256, 0, stream>>>(Apk, ATpk, BuT1, BiT1, Ptop, Pbot);
    k_reduce<<<768, 256, 0, stream>>>(Ptop, Pbot, dsu, dsi, acc, BuT0, BiT0, out, 1);
    k_gemm<<<2048, 256, 0, stream>>>(Apk, ATpk, BuT0, BiT0, Ptop, Pbot);
    k_reduce<<<768, 256, 0, stream>>>(Ptop, Pbot, dsu, dsi, acc,
                                      (u16*)nullptr, (u16*)nullptr, out, 2);
}